// Round 3
// baseline (333.963 us; speedup 1.0000x reference)
//
#include <hip/hip_runtime.h>
#include <float.h>

#define EMBED   64
#define CODES   4096
#define NROWS   65536      // 512*8192/64
#define NELEM   4194304    // 512*8192
#define BR      128        // rows per block (4 waves x 32 rows)
#define NCH     64         // 64-code chunks (2 tiles of 32), 16 KB each
#define NTILE   128        // 32-code tiles total

typedef __attribute__((ext_vector_type(8)))  short bf16x8;   // 8 bf16 in 4 VGPRs
typedef __attribute__((ext_vector_type(16))) float f32x16;   // MFMA 32x32 accumulator

__device__ inline unsigned short f2bf(float f) {             // RNE float->bf16
    unsigned u = __float_as_uint(f);
    u += 0x7fff + ((u >> 16) & 1);
    return (unsigned short)(u >> 16);
}
__device__ inline float bf2f(unsigned short h) {
    return __uint_as_float(((unsigned)h) << 16);
}

// ws layout: [0,16K) cbuf; [16K] double accum; [32K,32K+1M) packed B-frags; +1M ET
// Fused setup: blocks 0..15 cbuf(+accum), 16..143 pack, 144..399 ET.
__global__ void vq_setup(const float* __restrict__ E, float* __restrict__ cbuf,
                         double* __restrict__ accum, bf16x8* __restrict__ packed,
                         float* __restrict__ ET) {
    const int b = blockIdx.x, t = threadIdx.x;
    if (b < 16) {
        // cbuf: emulate np.sum(E*E, axis=0) (C-order: sequential i, mul/add rounded)
        int j = b * 256 + t;
        float v = E[j];
        float s = __fmul_rn(v, v);
        for (int i = 1; i < EMBED; ++i) {
            v = E[(size_t)i * CODES + j];
            s = __fadd_rn(s, __fmul_rn(v, v));
        }
        cbuf[j] = s;
        if (j == 0) *accum = 0.0;           // d_ws poisoned 0xAA before every launch
    } else if (b < 144) {
        // pack E into MFMA B-fragment order (both splits per thread)
        int id = (b - 16) * 256 + t;        // [0, 32768)
        int lam = id & 63, kk = (id >> 6) & 3, g = id >> 8;
        int n  = g * 32 + (lam & 31);
        int kb = kk * 16 + (lam >> 5) * 8;
        bf16x8 vh, vl;
#pragma unroll
        for (int j = 0; j < 8; ++j) {
            float e = E[(size_t)(kb + j) * CODES + n];
            unsigned short hi = f2bf(e);
            vh[j] = (short)hi;
            vl[j] = (short)f2bf(e - bf2f(hi));
        }
        packed[((g * 4 + kk) * 2 + 0) * 64 + lam] = vh;
        packed[((g * 4 + kk) * 2 + 1) * 64 + lam] = vl;
    } else {
        // ET = E^T (fp32) for the coalesced output gather / exact fallback
        int id = (b - 144) * 256 + t;       // [0, 65536)
        int j = id >> 4, i0 = (id & 15) * 4;
        float4 v;
        v.x = E[(size_t)(i0 + 0) * CODES + j];
        v.y = E[(size_t)(i0 + 1) * CODES + j];
        v.z = E[(size_t)(i0 + 2) * CODES + j];
        v.w = E[(size_t)(i0 + 3) * CODES + j];
        *(float4*)(ET + (size_t)j * EMBED + i0) = v;
    }
}

template <bool PRE>
__global__ __launch_bounds__(256, 2)
void vq_main(const float* __restrict__ X, const float* __restrict__ E,
             const float* __restrict__ cbuf, const bf16x8* __restrict__ packed,
             const float* __restrict__ ET, double* __restrict__ accum,
             float* __restrict__ out) {
    __shared__ float  cbuf_lds[CODES];       // 16 KB, loaded once
    __shared__ bf16x8 lbuf[3][1024];         // 3 x 16 KB chunk buffers (counted-vmcnt pipeline)

    const int t  = threadIdx.x;
    const int l  = t & 63, wv = t >> 6;
    const int m  = l & 31, h  = l >> 5;
    const int row0 = blockIdx.x * BR;

    // ---- A fragments (persistent): x split hi/lo; row ||x||^2 in reg ----
    bf16x8 ah[4], al[4];
    float sqreg;
    {
        const float* xrow = X + (size_t)(row0 + wv * 32 + m) * EMBED;
        float sq = 0.f;
#pragma unroll
        for (int kk = 0; kk < 4; ++kk) {
            int kb = kk * 16 + h * 8;
            float4 v0 = *(const float4*)(xrow + kb);
            float4 v1 = *(const float4*)(xrow + kb + 4);
            float xv[8] = {v0.x, v0.y, v0.z, v0.w, v1.x, v1.y, v1.z, v1.w};
#pragma unroll
            for (int j = 0; j < 8; ++j) {
                sq = fmaf(xv[j], xv[j], sq);
                unsigned short hi = f2bf(xv[j]);
                float r = xv[j] - bf2f(hi);
                ah[kk][j] = (short)hi;
                al[kk][j] = (short)f2bf(r);
            }
        }
        sq += __shfl_xor(sq, 32, 64);       // lanes l and l+32 hold same row
        sqreg = sq;
    }

    // top-2 of a = x.e - c/2 (max); tile index packed into low 7 mantissa bits
    float M1[16], M2[16];
#pragma unroll
    for (int e = 0; e < 16; ++e) { M1[e] = -FLT_MAX; M2[e] = -FLT_MAX; }

    auto epi = [&](const f32x16& a, int g) {      // 3 VALU per element
        unsigned gu = (unsigned)g;
#pragma unroll
        for (int e = 0; e < 16; ++e) {
            float ap = __uint_as_float((__float_as_uint(a[e]) & 0xFFFFFF80u) | gu);
            float m1o = M1[e];
            M1[e] = fmaxf(m1o, ap);
            M2[e] = __builtin_amdgcn_fmed3f(m1o, M2[e], ap);
        }
    };

    if constexpr (PRE) {
        auto stage = [&](int s, int bi) {     // 4 async 16B loads/thread per chunk
#pragma unroll
            for (int q = 0; q < 4; ++q) {
                const bf16x8* gp = packed + (size_t)s * 1024 + q * 256 + t;
                bf16x8* lp = &lbuf[bi][q * 256 + wv * 64];  // wave-uniform base +lane*16
                __builtin_amdgcn_global_load_lds(
                    (const __attribute__((address_space(1))) void*)gp,
                    (__attribute__((address_space(3))) void*)lp, 16, 0, 0);
            }
        };

        // prologue bundle: cbuf -> LDS (4 loads), then chunks s0, s0+1
#pragma unroll
        for (int q = 0; q < 4; ++q) {
            const float* gp = cbuf + (size_t)(q * 256 + t) * 4;
            char* lp = (char*)cbuf_lds + (size_t)(q * 256 + wv * 64) * 16;
            __builtin_amdgcn_global_load_lds(
                (const __attribute__((address_space(1))) void*)gp,
                (__attribute__((address_space(3))) void*)lp, 16, 0, 0);
        }
        const int s0 = blockIdx.x & (NCH - 1);   // rotate chunk order across blocks
        stage(s0, 0);
        stage((s0 + 1) & (NCH - 1), 1);

        // software pipeline regs: prev-chunk accumulators, epilogue delayed
        f32x16 pA, pB; int pGA = 0, pGB = 0;
#pragma unroll
        for (int e = 0; e < 16; ++e) { pA[e] = -FLT_MAX; pB[e] = -FLT_MAX; }  // harmless dummy

        // cbuf + chunk s0 landed; chunk s0+1 (newest 4 loads) may stay in flight
        asm volatile("s_waitcnt vmcnt(4)" ::: "memory");
        __builtin_amdgcn_sched_barrier(0);
        __builtin_amdgcn_s_barrier();
        __builtin_amdgcn_sched_barrier(0);

        int bi = 0;
#pragma unroll 1
        for (int cc = 0; cc < NCH; ++cc) {
            int s = s0 + cc; if (s >= NCH) s -= NCH;
            const bf16x8* lb = lbuf[bi];
            const int g0 = 2 * s, g1 = g0 + 1;
            // per-tile -c/2 from LDS (free 2-way broadcast; no VMEM in loop)
            float nc0 = -0.5f * cbuf_lds[g0 * 32 + m];
            float nc1 = -0.5f * cbuf_lds[g1 * 32 + m];
            bf16x8 B0[8], B1[8];
#pragma unroll
            for (int kk = 0; kk < 4; ++kk) {
                B0[kk * 2]     = lb[kk * 128 + l];
                B0[kk * 2 + 1] = lb[kk * 128 + 64 + l];
                B1[kk * 2]     = lb[512 + kk * 128 + l];
                B1[kk * 2 + 1] = lb[512 + kk * 128 + 64 + l];
            }
            // delayed epilogue of previous chunk: independent VALU fills the
            // lgkm shadow and co-issues with MFMA
            epi(pA, pGA);
            epi(pB, pGB);
            f32x16 a0, a1;
#pragma unroll
            for (int e = 0; e < 16; ++e) { a0[e] = nc0; a1[e] = nc1; }
#pragma unroll
            for (int kk = 0; kk < 4; ++kk) {  // two interleaved chains, gap 2
                a0 = __builtin_amdgcn_mfma_f32_32x32x16_bf16(ah[kk], B0[kk * 2],     a0, 0, 0, 0);
                a1 = __builtin_amdgcn_mfma_f32_32x32x16_bf16(ah[kk], B1[kk * 2],     a1, 0, 0, 0);
                a0 = __builtin_amdgcn_mfma_f32_32x32x16_bf16(ah[kk], B0[kk * 2 + 1], a0, 0, 0, 0);
                a1 = __builtin_amdgcn_mfma_f32_32x32x16_bf16(ah[kk], B1[kk * 2 + 1], a1, 0, 0, 0);
                a0 = __builtin_amdgcn_mfma_f32_32x32x16_bf16(al[kk], B0[kk * 2],     a0, 0, 0, 0);
                a1 = __builtin_amdgcn_mfma_f32_32x32x16_bf16(al[kk], B1[kk * 2],     a1, 0, 0, 0);
            }
            pA = a0; pB = a1; pGA = g0; pGB = g1;

            // counted-vmcnt pipeline: stage chunk cc+2, keep it in flight across
            // the barrier; require only chunk cc+1 (previous bundle) landed.
            if (cc < NCH - 2) {
                int sn = s + 2; if (sn >= NCH) sn -= NCH;
                int sb = bi + 2; if (sb >= 3) sb -= 3;
                stage(sn, sb);
                asm volatile("s_waitcnt vmcnt(4)" ::: "memory");
            } else {
                asm volatile("s_waitcnt vmcnt(0)" ::: "memory");
            }
            __builtin_amdgcn_sched_barrier(0);
            __builtin_amdgcn_s_barrier();
            __builtin_amdgcn_sched_barrier(0);
            if (++bi == 3) bi = 0;
        }
        epi(pA, pGA);
        epi(pB, pGB);
    } else {
        // fallback path (no workspace): convert E on the fly per tile
#pragma unroll 1
        for (int g = 0; g < NTILE; ++g) {
            bf16x8 B[8];
            int n = g * 32 + m;
#pragma unroll
            for (int kk = 0; kk < 4; ++kk) {
                const float* ec = E + (size_t)(kk * 16 + h * 8) * CODES + n;
                bf16x8 vh, vl;
#pragma unroll
                for (int j = 0; j < 8; ++j) {
                    float e = ec[(size_t)j * CODES];
                    unsigned short hi = f2bf(e);
                    vh[j] = (short)hi;
                    vl[j] = (short)f2bf(e - bf2f(hi));
                }
                B[kk * 2] = vh; B[kk * 2 + 1] = vl;
            }
            float nc = -0.5f * cbuf[g * 32 + m];
            f32x16 acc;
#pragma unroll
            for (int e = 0; e < 16; ++e) acc[e] = nc;
#pragma unroll
            for (int kk = 0; kk < 4; ++kk) {
                acc = __builtin_amdgcn_mfma_f32_32x32x16_bf16(ah[kk], B[kk * 2],     acc, 0, 0, 0);
                acc = __builtin_amdgcn_mfma_f32_32x32x16_bf16(ah[kk], B[kk * 2 + 1], acc, 0, 0, 0);
                acc = __builtin_amdgcn_mfma_f32_32x32x16_bf16(al[kk], B[kk * 2],     acc, 0, 0, 0);
            }
            epi(acc, g);
        }
        __syncthreads();
    }

    // lbuf dead -> overlay scratch
    float* rowm1  = (float*)&lbuf[0][0];
    float* rowsq  = rowm1 + BR;
    int*   rowidx = (int*)(rowsq + BR);
    int*   rowflg = rowidx + BR;
    float* fredv  = (float*)(rowflg + BR);
    int*   fredi  = (int*)(fredv + 256);

    // extract indices from packed scores, then cross-lane top-2 merge
    int I1[16];
#pragma unroll
    for (int e = 0; e < 16; ++e)
        I1[e] = (int)(((__float_as_uint(M1[e]) & 0x7Fu) << 5) | (unsigned)m);
#pragma unroll
    for (int d = 1; d < 32; d <<= 1) {
#pragma unroll
        for (int e = 0; e < 16; ++e) {
            float oM1 = __shfl_xor(M1[e], d, 64);
            float oM2 = __shfl_xor(M2[e], d, 64);
            int   oI  = __shfl_xor(I1[e], d, 64);
            float lo  = fminf(M1[e], oM1);
            M2[e] = fmaxf(lo, fmaxf(M2[e], oM2));
            bool c = oM1 > M1[e];
            I1[e] = c ? oI : I1[e];
            M1[e] = c ? oM1 : M1[e];
        }
    }
    if (h == 0) rowsq[wv * 32 + m] = sqreg;
    // C/D row = (reg&3) + 8*(reg>>2) + 4*(lane>>5); one lane writes each row
#pragma unroll
    for (int e = 0; e < 16; ++e) {
        int r = (e & 3) + 8 * (e >> 2) + 4 * h;
        if (m == r) {
            rowm1[wv * 32 + r]  = __uint_as_float(__float_as_uint(M1[e]) & 0xFFFFFF80u);
            rowidx[wv * 32 + r] = I1[e];
            rowflg[wv * 32 + r] = (2.f * (M1[e] - M2[e]) < 2e-4f) ? 1 : 0;
        }
    }
    __syncthreads();

    // ---- rare fallback: bit-exact fp32 numpy-reference emulation (uniform branch) ----
#pragma unroll 1
    for (int r = 0; r < BR; ++r) {
        if (rowflg[r] == 0) continue;
        const float* xr = X + (size_t)(row0 + r) * EMBED;
        float racc[8];
#pragma unroll
        for (int jq = 0; jq < 8; ++jq) racc[jq] = __fmul_rn(xr[jq], xr[jq]);
#pragma unroll
        for (int i = 8; i < 64; i += 8)
#pragma unroll
            for (int jq = 0; jq < 8; ++jq)
                racc[jq] = __fadd_rn(racc[jq], __fmul_rn(xr[i + jq], xr[i + jq]));
        float A = __fadd_rn(
            __fadd_rn(__fadd_rn(racc[0], racc[1]), __fadd_rn(racc[2], racc[3])),
            __fadd_rn(__fadd_rn(racc[4], racc[5]), __fadd_rn(racc[6], racc[7])));

        float best = FLT_MAX; int bestj = CODES;
#pragma unroll 1
        for (int jj = 0; jj < 16; ++jj) {
            int j = jj * 256 + t;
            float mm = 0.f;
            if constexpr (PRE) {
                const float* er = ET + (size_t)j * EMBED;   // contiguous, same bits as E column
#pragma unroll
                for (int i = 0; i < 64; ++i)
                    mm = fmaf(xr[i], er[i], mm);            // sequential FMA (BLAS k-loop)
            } else {
#pragma unroll
                for (int i = 0; i < 64; ++i)
                    mm = fmaf(xr[i], E[(size_t)i * CODES + j], mm);
            }
            float d = __fadd_rn(__fsub_rn(A, __fmul_rn(2.f, mm)), cbuf[j]);
            if (d < best || (d == best && j < bestj)) { best = d; bestj = j; }
        }
        fredv[t] = best; fredi[t] = bestj;
        __syncthreads();
        if (t == 0) {
            float B = fredv[0]; int BI = fredi[0];
            for (int c2 = 1; c2 < 256; ++c2) {
                float dc = fredv[c2]; int jc = fredi[c2];
                if (dc < B || (dc == B && jc < BI)) { B = dc; BI = jc; }
            }
            rowidx[r] = BI;
        }
        __syncthreads();
    }

    // ---- outputs ----
    if (t < BR) out[(size_t)NELEM + 1 + row0 + t] = (float)rowidx[t];  // idx as float
    if (t == 0) {
        float bs = 0.f;
        for (int r = 0; r < BR; ++r) bs += rowsq[r] - 2.f * rowm1[r];  // sum (x-e)^2
        atomicAdd(accum, (double)bs);
    }
    {
        int r = t >> 1, i0 = (t & 1) * 32;
        int j = rowidx[r];
        float* dst = out + (size_t)(row0 + r) * EMBED + i0;
        if constexpr (PRE) {
            const float* src = ET + (size_t)j * EMBED + i0;
#pragma unroll
            for (int g = 0; g < 8; ++g)
                *(float4*)(dst + g * 4) = *(const float4*)(src + g * 4);
        } else {
#pragma unroll
            for (int g = 0; g < 8; ++g) {
                float4 v;
                v.x = E[(size_t)(i0 + g * 4 + 0) * CODES + j];
                v.y = E[(size_t)(i0 + g * 4 + 1) * CODES + j];
                v.z = E[(size_t)(i0 + g * 4 + 2) * CODES + j];
                v.w = E[(size_t)(i0 + g * 4 + 3) * CODES + j];
                *(float4*)(dst + g * 4) = v;
            }
        }
    }
}

__global__ void vq_finalize(const double* __restrict__ accum, float* __restrict__ out) {
    out[NELEM] = (float)(0.25 * (*accum) / (double)NELEM);
}

extern "C" void kernel_launch(void* const* d_in, const int* in_sizes, int n_in,
                              void* d_out, int out_size, void* d_ws, size_t ws_size,
                              hipStream_t stream) {
    const float* X = (const float*)d_in[0];   // (512, 8192, 1) f32 -> 65536 rows x 64
    const float* E = (const float*)d_in[1];   // (64, 4096) f32 row-major
    float* out = (float*)d_out;
    float*  cbuf   = (float*)d_ws;
    double* accum  = (double*)((char*)d_ws + 16384);
    bf16x8* packed = (bf16x8*)((char*)d_ws + 32768);
    float*  ET     = (float*)((char*)d_ws + 32768 + 1048576);
    const size_t need = 32768 + 1048576 + 1048576;
    const bool pre = (ws_size >= need);       // constant across calls -> same work every call

    vq_setup<<<pre ? 400 : 16, 256, 0, stream>>>(E, cbuf, accum, packed, ET);
    if (pre)
        vq_main<true><<<NROWS / BR, 256, 0, stream>>>(X, E, cbuf, packed, ET, accum, out);
    else
        vq_main<false><<<NROWS / BR, 256, 0, stream>>>(X, E, cbuf, packed, ET, accum, out);
    vq_finalize<<<1, 1, 0, stream>>>(accum, out);
}